// Round 1
// baseline (1350.445 us; speedup 1.0000x reference)
//
#include <hip/hip_runtime.h>
#include <hip/hip_bf16.h>

typedef __bf16 bf16_t;
typedef __bf16 bf16x8v __attribute__((ext_vector_type(8)));
typedef __bf16 bf16x4v __attribute__((ext_vector_type(4)));
typedef float f32x4 __attribute__((ext_vector_type(4)));

#define NN 12000
#define FF 256

// ---------------- scores: scores[r] = dot(input[r,:], attn) ----------------
__global__ void scores_kernel(const float* __restrict__ input, const float* __restrict__ attn,
                              float* __restrict__ scores)
{
    int tid  = threadIdx.x;
    int lane = tid & 63;
    int r    = blockIdx.x * 4 + (tid >> 6);   // grid = NN/4, one wave per row
    const float4 x = *(const float4*)(input + (size_t)r * FF + lane * 4);
    const float4 a = *(const float4*)(attn + lane * 4);
    float s = x.x * a.x + x.y * a.y + x.z * a.z + x.w * a.w;
#pragma unroll
    for (int off = 32; off > 0; off >>= 1) s += __shfl_down(s, off);
    if (lane == 0) scores[r] = s;
}

// ---------------- softmax over all N scores, in place -> p[r] ----------------
__global__ void softmax_kernel(float* __restrict__ s, int n)
{
    __shared__ float red[16];
    __shared__ float bc[2];
    int tid = threadIdx.x, lane = tid & 63, w = tid >> 6;

    float mx = -1e30f;
    for (int i = tid; i < n; i += 1024) mx = fmaxf(mx, s[i]);
#pragma unroll
    for (int o = 32; o > 0; o >>= 1) mx = fmaxf(mx, __shfl_down(mx, o));
    if (lane == 0) red[w] = mx;
    __syncthreads();
    if (tid == 0) {
        float m = red[0];
        for (int i = 1; i < 16; ++i) m = fmaxf(m, red[i]);
        bc[0] = m;
    }
    __syncthreads();
    float M = bc[0];

    float sum = 0.f;
    for (int i = tid; i < n; i += 1024) sum += __expf(s[i] - M);
#pragma unroll
    for (int o = 32; o > 0; o >>= 1) sum += __shfl_down(sum, o);
    if (lane == 0) red[w] = sum;
    __syncthreads();
    if (tid == 0) {
        float t = 0.f;
        for (int i = 0; i < 16; ++i) t += red[i];
        bc[1] = t;
    }
    __syncthreads();
    float inv = 1.0f / bc[1];
    for (int i = tid; i < n; i += 1024) s[i] = __expf(s[i] - M) * inv;
}

// ------- transpose (+optional per-row scale) fp32[R][256] -> bf16[256][R] -------
__global__ void transpose_scale_kernel(const float* __restrict__ src, const float* __restrict__ p,
                                       bf16_t* __restrict__ dst, int R)
{
    __shared__ float T[64][65];
    int tid = threadIdx.x;
    int r0 = blockIdx.x * 64;
    int c0 = blockIdx.y * 64;
    int j = (tid & 15) * 4;
#pragma unroll
    for (int i = 0; i < 4; ++i) {
        int rl = (tid >> 4) + 16 * i;
        int gr = r0 + rl;
        float4 v = {0.f, 0.f, 0.f, 0.f};
        float sc = 1.f;
        if (gr < R) {
            v = *(const float4*)(src + (size_t)gr * FF + c0 + j);
            if (p) sc = p[gr];
        }
        T[rl][j + 0] = v.x * sc;
        T[rl][j + 1] = v.y * sc;
        T[rl][j + 2] = v.z * sc;
        T[rl][j + 3] = v.w * sc;
    }
    __syncthreads();
#pragma unroll
    for (int i = 0; i < 2; ++i) {
        int idx = tid + 256 * i;
        int cl = idx >> 3;
        int rr = (idx & 7) * 8;
        if (r0 + rr < R) {   // R % 8 == 0, chunk all-in or all-out
            bf16x8v v;
#pragma unroll
            for (int e = 0; e < 8; ++e) v[e] = (bf16_t)T[rr + e][cl];
            *(bf16x8v*)(dst + (size_t)(c0 + cl) * R + r0 + rr) = v;
        }
    }
}

// ---------------- MFMA GEMM: C[M,256] = A[M,K](fp32) x Bt[256,K](bf16)^T ----------------
// MODE 0: write fp32 partial to Cpart + blockIdx.y*part_stride (split-K)
// MODE 1: write transposed bf16 to Ct[256][M] (single split)
template <int MODE>
__global__ __launch_bounds__(256, 3)
void gemm_kernel(const float* __restrict__ A, const bf16_t* __restrict__ Bt,
                 float* __restrict__ Cpart, size_t part_stride,
                 bf16_t* __restrict__ Ct,
                 int M, int K, int sps, int total_steps)
{
    constexpr int LDSA  = 64 * 40;        // padded stride 40 bf16 (80 B = 5*16 B)
    constexpr int LDSB  = 256 * 40;
    constexpr int STAGE = LDSA + LDSB;    // 12800 elems
    constexpr int EPI   = 256 * 72;       // 18432 elems (MODE 1 transpose bounce)
    __shared__ __align__(16) bf16_t smem[(MODE == 1) ? (STAGE > EPI ? STAGE : EPI) : STAGE];
    bf16_t* As = smem;
    bf16_t* Bs = smem + LDSA;

    const int tid  = threadIdx.x;
    const int wave = tid >> 6;
    const int lane = tid & 63;
    const int quad = lane >> 4;
    const int l16  = lane & 15;
    const int row0   = blockIdx.x * 64;
    const int step0  = blockIdx.y * sps;
    const int nsteps = min(sps, total_steps - step0);

    f32x4 acc[4][4];
#pragma unroll
    for (int i = 0; i < 4; ++i)
#pragma unroll
        for (int j = 0; j < 4; ++j)
            acc[i][j] = (f32x4){0.f, 0.f, 0.f, 0.f};

    const int a_kq = (tid & 7) * 4;   // fp32 quad within 32-k row
    const int a_r  = tid >> 3;        // 0..31 (+32)
    const int b_kq = (tid & 3) * 8;   // bf16 oct within 32-k row
    const int b_n  = tid >> 2;        // 0..63 (+64*i)
    const int qk   = quad * 8;

    for (int s = 0; s < nsteps; ++s) {
        const int k0 = (step0 + s) * 32;
        // stage A tile 64x32 fp32 -> bf16 (coalesced float4, convert, 8B ds_write)
#pragma unroll
        for (int i = 0; i < 2; ++i) {
            int r = a_r + 32 * i;
            int gr = row0 + r;
            float4 v = {0.f, 0.f, 0.f, 0.f};
            if (gr < M) v = *(const float4*)(A + (size_t)gr * K + k0 + a_kq);
            bf16x4v w;
            w[0] = (bf16_t)v.x; w[1] = (bf16_t)v.y; w[2] = (bf16_t)v.z; w[3] = (bf16_t)v.w;
            *(bf16x4v*)(As + r * 40 + a_kq) = w;
        }
        // stage Bt tile 256x32 bf16 (16B loads, 16B ds_write)
#pragma unroll
        for (int i = 0; i < 4; ++i) {
            int n = b_n + 64 * i;
            bf16x8v v = *(const bf16x8v*)(Bt + (size_t)n * K + k0 + b_kq);
            *(bf16x8v*)(Bs + n * 40 + b_kq) = v;
        }
        __syncthreads();
        bf16x8v af[4], bfr[4];
#pragma unroll
        for (int t = 0; t < 4; ++t) {
            af[t]  = *(const bf16x8v*)(As + (16 * t + l16) * 40 + qk);
            bfr[t] = *(const bf16x8v*)(Bs + (wave * 64 + 16 * t + l16) * 40 + qk);
        }
#pragma unroll
        for (int im = 0; im < 4; ++im)
#pragma unroll
            for (int in = 0; in < 4; ++in)
                acc[im][in] = __builtin_amdgcn_mfma_f32_16x16x32_bf16(af[im], bfr[in], acc[im][in], 0, 0, 0);
        __syncthreads();
    }

    if (MODE == 0) {
        float* Cp = Cpart + (size_t)blockIdx.y * part_stride;
#pragma unroll
        for (int im = 0; im < 4; ++im)
#pragma unroll
            for (int in = 0; in < 4; ++in) {
                int n = wave * 64 + 16 * in + l16;
#pragma unroll
                for (int rg = 0; rg < 4; ++rg) {
                    int r = row0 + 16 * im + 4 * quad + rg;
                    if (r < M) Cp[(size_t)r * FF + n] = acc[im][in][rg];
                }
            }
    } else {
        // transpose epilogue: acc -> LDS [256 n][72] -> bf16 Ct[256][M]
        constexpr int TS = 72;   // 144 B row = 9*16 B, aligned
        bf16_t* T = smem;
#pragma unroll
        for (int im = 0; im < 4; ++im)
#pragma unroll
            for (int in = 0; in < 4; ++in) {
                int n  = wave * 64 + 16 * in + l16;
                int mb = 16 * im + 4 * quad;
                bf16x4v w;
#pragma unroll
                for (int rg = 0; rg < 4; ++rg) w[rg] = (bf16_t)acc[im][in][rg];
                *(bf16x4v*)(T + n * TS + mb) = w;
            }
        __syncthreads();
#pragma unroll
        for (int i = 0; i < 8; ++i) {
            int idx = tid + 256 * i;
            int n  = idx >> 3;
            int mc = (idx & 7) * 8;
            if (row0 + mc < M) {   // M % 8 == 0, chunk all-in or all-out
                bf16x8v v = *(const bf16x8v*)(T + n * TS + mc);
                *(bf16x8v*)(Ct + (size_t)n * M + row0 + mc) = v;
            }
        }
    }
}

// ------- reduce split-K partials (+ optional alpha*addsrc), fp32 float4 -------
__global__ void reduce_parts_kernel(const float* __restrict__ parts, size_t part_stride,
                                    int nsplit,
                                    const float* __restrict__ addsrc, const float* __restrict__ alpha,
                                    float* __restrict__ out, int count4)
{
    int i = blockIdx.x * 256 + threadIdx.x;
    if (i >= count4) return;
    f32x4 s = ((const f32x4*)parts)[i];
    for (int sp = 1; sp < nsplit; ++sp) {
        f32x4 v = *(const f32x4*)(parts + (size_t)sp * part_stride + (size_t)i * 4);
        s += v;
    }
    if (addsrc) {
        float a = alpha[0];
        f32x4 v = ((const f32x4*)addsrc)[i];
        s += v * a;
    }
    ((f32x4*)out)[i] = s;
}

extern "C" void kernel_launch(void* const* d_in, const int* in_sizes, int n_in,
                              void* d_out, int out_size, void* d_ws, size_t ws_size,
                              hipStream_t stream)
{
    const float* input  = (const float*)d_in[0];
    const float* adj    = (const float*)d_in[1];
    const float* inc    = (const float*)d_in[2];
    const float* weight = (const float*)d_in[3];
    const float* attn   = (const float*)d_in[4];
    const float* alpha  = (const float*)d_in[5];
    float* out = (float*)d_out;

    char* ws = (char*)d_ws;
    size_t off = 0;
    auto take = [&](size_t bytes) {
        char* p = ws + off;
        off = (off + bytes + 255) & ~(size_t)255;
        return p;
    };
    bf16_t* scaledT  = (bf16_t*)take((size_t)FF * NN * 2);   // scaled^T  [256][12000]
    bf16_t* supportT = (bf16_t*)take((size_t)FF * NN * 2);   // support^T [256][12000]
    bf16_t* weightT  = (bf16_t*)take((size_t)FF * FF * 2);   // weight^T  [256][256]
    float*  support4 = (float*)take((size_t)NN * FF * 4);    // adj@scaled + alpha*input
    float*  scores   = (float*)take((size_t)NN * 4);         // scores -> softmax p

    const size_t part_elems = (size_t)NN * FF;               // fp32 elems per split partial
    int splits = 4;
    while (splits > 1 && off + (size_t)splits * part_elems * 4 > ws_size) --splits;
    float* parts = (float*)take((size_t)splits * part_elems * 4);

    const int total_steps = NN / 32;                         // 375
    const int sps = (total_steps + splits - 1) / splits;     // 94 for splits=4
    const int mblocks = (NN + 63) / 64;                      // 188
    const int red_blocks = (NN * FF / 4 + 255) / 256;

    scores_kernel<<<NN / 4, 256, 0, stream>>>(input, attn, scores);
    softmax_kernel<<<1, 1024, 0, stream>>>(scores, NN);
    transpose_scale_kernel<<<dim3(mblocks, FF / 64), 256, 0, stream>>>(input, scores, scaledT, NN);
    transpose_scale_kernel<<<dim3(FF / 64, FF / 64), 256, 0, stream>>>(weight, nullptr, weightT, FF);

    // support3 partials = adj @ scaled
    gemm_kernel<0><<<dim3(mblocks, splits), 256, 0, stream>>>(
        adj, scaledT, parts, part_elems, nullptr, NN, NN, sps, total_steps);
    // support4 = sum(partials) + alpha*input
    reduce_parts_kernel<<<red_blocks, 256, 0, stream>>>(
        parts, part_elems, splits, input, alpha, support4, NN * FF / 4);
    // support^T (bf16) = (support4 @ weight)^T
    gemm_kernel<1><<<dim3(mblocks, 1), 256, 0, stream>>>(
        support4, weightT, nullptr, 0, supportT, NN, FF, FF / 32, FF / 32);
    // output partials = incidence @ support
    gemm_kernel<0><<<dim3(mblocks, splits), 256, 0, stream>>>(
        inc, supportT, parts, part_elems, nullptr, NN, NN, sps, total_steps);
    reduce_parts_kernel<<<red_blocks, 256, 0, stream>>>(
        parts, part_elems, splits, nullptr, nullptr, out, NN * FF / 4);
}

// Round 3
// 1232.623 us; speedup vs baseline: 1.0956x; 1.0956x over previous
//
#include <hip/hip_runtime.h>
#include <hip/hip_bf16.h>

typedef __bf16 bf16_t;
typedef __bf16 bf16x8v __attribute__((ext_vector_type(8)));
typedef __bf16 bf16x4v __attribute__((ext_vector_type(4)));
typedef float f32x4 __attribute__((ext_vector_type(4)));

#define NN 12000
#define FF 256

// ---------------- scores: scores[r] = dot(input[r,:], attn) ----------------
__global__ void scores_kernel(const float* __restrict__ input, const float* __restrict__ attn,
                              float* __restrict__ scores)
{
    int tid  = threadIdx.x;
    int lane = tid & 63;
    int r    = blockIdx.x * 4 + (tid >> 6);   // grid = NN/4, one wave per row
    const float4 x = *(const float4*)(input + (size_t)r * FF + lane * 4);
    const float4 a = *(const float4*)(attn + lane * 4);
    float s = x.x * a.x + x.y * a.y + x.z * a.z + x.w * a.w;
#pragma unroll
    for (int off = 32; off > 0; off >>= 1) s += __shfl_down(s, off);
    if (lane == 0) scores[r] = s;
}

// ---------------- softmax over all N scores, in place ----------------
__global__ void softmax_kernel(float* __restrict__ s, int n)
{
    __shared__ float red[16];
    __shared__ float bc[2];
    int tid = threadIdx.x, lane = tid & 63, w = tid >> 6;

    float mx = -1e30f;
    for (int i = tid; i < n; i += 1024) mx = fmaxf(mx, s[i]);
#pragma unroll
    for (int o = 32; o > 0; o >>= 1) mx = fmaxf(mx, __shfl_down(mx, o));
    if (lane == 0) red[w] = mx;
    __syncthreads();
    if (tid == 0) {
        float m = red[0];
        for (int i = 1; i < 16; ++i) m = fmaxf(m, red[i]);
        bc[0] = m;
    }
    __syncthreads();
    float M = bc[0];

    float sum = 0.f;
    for (int i = tid; i < n; i += 1024) sum += __expf(s[i] - M);
#pragma unroll
    for (int o = 32; o > 0; o >>= 1) sum += __shfl_down(sum, o);
    if (lane == 0) red[w] = sum;
    __syncthreads();
    if (tid == 0) {
        float t = 0.f;
        for (int i = 0; i < 16; ++i) t += red[i];
        bc[1] = t;
    }
    __syncthreads();
    float inv = 1.0f / bc[1];
    for (int i = tid; i < n; i += 1024) s[i] = __expf(s[i] - M) * inv;
}

// ------- transpose (+optional per-row scale) fp32[R][256] -> bf16[256][R] -------
__global__ void transpose_scale_kernel(const float* __restrict__ src, const float* __restrict__ p,
                                       bf16_t* __restrict__ dst, int R)
{
    __shared__ float T[64][65];
    int tid = threadIdx.x;
    int r0 = blockIdx.x * 64;
    int c0 = blockIdx.y * 64;
    int j = (tid & 15) * 4;
#pragma unroll
    for (int i = 0; i < 4; ++i) {
        int rl = (tid >> 4) + 16 * i;
        int gr = r0 + rl;
        float4 v = {0.f, 0.f, 0.f, 0.f};
        float sc = 1.f;
        if (gr < R) {
            v = *(const float4*)(src + (size_t)gr * FF + c0 + j);
            if (p) sc = p[gr];
        }
        T[rl][j + 0] = v.x * sc;
        T[rl][j + 1] = v.y * sc;
        T[rl][j + 2] = v.z * sc;
        T[rl][j + 3] = v.w * sc;
    }
    __syncthreads();
#pragma unroll
    for (int i = 0; i < 2; ++i) {
        int idx = tid + 256 * i;
        int cl = idx >> 3;
        int rr = (idx & 7) * 8;
        if (r0 + rr < R) {   // R % 8 == 0, chunk all-in or all-out
            bf16x8v v;
#pragma unroll
            for (int e = 0; e < 8; ++e) v[e] = (bf16_t)T[rr + e][cl];
            *(bf16x8v*)(dst + (size_t)(c0 + cl) * R + r0 + rr) = v;
        }
    }
}

// ---------------- MFMA GEMM: C[M,256] = A[M,K](fp32) x Bt[256,K](bf16)^T ----------------
// 128x256 tile, 512 threads (8 waves, each 64x64 = 4x4 frags of 16x16x32).
// Software-pipelined: step s+1 global loads issued between the two barriers of step s.
// MODE 0: write fp32 partial to Cpart + blockIdx.y*part_stride (split-K)
// MODE 1: write transposed bf16 to Ct[256][M] (single split)
template <int MODE>
__global__ __launch_bounds__(512, 4)
void gemm_kernel(const float* __restrict__ A, const bf16_t* __restrict__ Bt,
                 float* __restrict__ Cpart, size_t part_stride,
                 bf16_t* __restrict__ Ct,
                 int M, int K, int sps, int total_steps)
{
    constexpr int LDSA  = 128 * 40;       // padded stride 40 bf16 (80 B), conflict-free
    constexpr int LDSB  = 256 * 40;
    constexpr int STAGE = LDSA + LDSB;    // 15360 elems = 30.7 KB
    constexpr int EPI   = 256 * 136;      // MODE 1 transpose bounce (272 B rows, 16B-aligned)
    __shared__ __align__(16) bf16_t smem[(MODE == 1) ? (STAGE > EPI ? STAGE : EPI) : STAGE];
    bf16_t* As = smem;
    bf16_t* Bs = smem + LDSA;

    const int tid  = threadIdx.x;
    const int wave = tid >> 6;
    const int lane = tid & 63;
    const int quad = lane >> 4;
    const int l16  = lane & 15;
    const int wr   = wave >> 2;           // 0..1 row-group (64 rows)
    const int wc   = wave & 3;            // 0..3 col-group (64 cols)
    const int qk   = quad * 8;

    const int row0   = blockIdx.x * 128;
    const int step0  = blockIdx.y * sps;
    const int nsteps = min(sps, total_steps - step0);

    f32x4 acc[4][4];
#pragma unroll
    for (int i = 0; i < 4; ++i)
#pragma unroll
        for (int j = 0; j < 4; ++j)
            acc[i][j] = (f32x4){0.f, 0.f, 0.f, 0.f};

    // A staging: thread t -> row t>>2 (0..127), k-oct (t&3)*8 (8 fp32 = 2 float4)
    const int a_row = tid >> 2;
    const int a_ko  = (tid & 3) * 8;
    // clamp OOB rows to row 0 (value is irrelevant: C rows >= M are never stored)
    const int a_row_safe = ((row0 + a_row) < M) ? a_row : 0;
    const float* Ap = A + (size_t)(row0 + a_row_safe) * K + a_ko;
    bf16_t* As_w = As + a_row * 40 + a_ko;
    // B staging: 1024 16B-chunks, 2 per thread: c = tid, tid+512 -> row c>>2, k-oct (c&3)*8
    const int b_n0 = tid >> 2;
    const int b_k0 = (tid & 3) * 8;
    const int b_n1 = (tid + 512) >> 2;
    const int b_k1 = ((tid + 512) & 3) * 8;
    const bf16_t* Bp0 = Bt + (size_t)b_n0 * K + b_k0;
    const bf16_t* Bp1 = Bt + (size_t)b_n1 * K + b_k1;
    bf16_t* Bs_w0 = Bs + b_n0 * 40 + b_k0;
    bf16_t* Bs_w1 = Bs + b_n1 * 40 + b_k1;

    float4 av0, av1;
    bf16x8v bv0, bv1;
    auto issue = [&](int s) {
        const int k = (step0 + s) * 32;
        av0 = *(const float4*)(Ap + k);
        av1 = *(const float4*)(Ap + k + 4);
        bv0 = *(const bf16x8v*)(Bp0 + k);
        bv1 = *(const bf16x8v*)(Bp1 + k);
    };

    issue(0);
    for (int s = 0; s < nsteps; ++s) {
        bf16x8v aw;
        aw[0] = (bf16_t)av0.x; aw[1] = (bf16_t)av0.y; aw[2] = (bf16_t)av0.z; aw[3] = (bf16_t)av0.w;
        aw[4] = (bf16_t)av1.x; aw[5] = (bf16_t)av1.y; aw[6] = (bf16_t)av1.z; aw[7] = (bf16_t)av1.w;
        bf16x8v bw0 = bv0, bw1 = bv1;
        __syncthreads();                      // previous step's frag reads complete
        *(bf16x8v*)As_w  = aw;
        *(bf16x8v*)Bs_w0 = bw0;
        *(bf16x8v*)Bs_w1 = bw1;
        if (s + 1 < nsteps) issue(s + 1);     // overlap next loads with this step's MFMA
        __syncthreads();

        bf16x8v af[4];
#pragma unroll
        for (int t = 0; t < 4; ++t)
            af[t] = *(const bf16x8v*)(As + (wr * 64 + 16 * t + l16) * 40 + qk);
#pragma unroll
        for (int in = 0; in < 4; ++in) {
            bf16x8v bfr = *(const bf16x8v*)(Bs + (wc * 64 + 16 * in + l16) * 40 + qk);
#pragma unroll
            for (int im = 0; im < 4; ++im)
                acc[im][in] = __builtin_amdgcn_mfma_f32_16x16x32_bf16(af[im], bfr, acc[im][in], 0, 0, 0);
        }
    }

    if (MODE == 0) {
        float* Cp = Cpart + (size_t)blockIdx.y * part_stride;
#pragma unroll
        for (int im = 0; im < 4; ++im)
#pragma unroll
            for (int in = 0; in < 4; ++in) {
                int n = wc * 64 + 16 * in + l16;
#pragma unroll
                for (int rg = 0; rg < 4; ++rg) {
                    int r = row0 + wr * 64 + 16 * im + 4 * quad + rg;
                    if (r < M) Cp[(size_t)r * FF + n] = acc[im][in][rg];
                }
            }
    } else {
        // transpose epilogue: acc -> LDS [256 n][136] -> bf16 Ct[256][M]
        constexpr int TS = 136;
        bf16_t* T = smem;
        __syncthreads();   // done with stage buffers
#pragma unroll
        for (int im = 0; im < 4; ++im)
#pragma unroll
            for (int in = 0; in < 4; ++in) {
                int n  = wc * 64 + 16 * in + l16;
                int mb = wr * 64 + 16 * im + 4 * quad;
                bf16x4v w;
#pragma unroll
                for (int rg = 0; rg < 4; ++rg) w[rg] = (bf16_t)acc[im][in][rg];
                *(bf16x4v*)(T + n * TS + mb) = w;
            }
        __syncthreads();
#pragma unroll
        for (int i = 0; i < 8; ++i) {
            int idx = tid + 512 * i;          // 0..4095: 256 rows x 16 chunks
            int n  = idx >> 4;
            int mc = (idx & 15) * 8;
            if (row0 + mc < M) {              // M % 8 == 0, chunk all-in or all-out
                bf16x8v v = *(const bf16x8v*)(T + n * TS + mc);
                *(bf16x8v*)(Ct + (size_t)n * M + row0 + mc) = v;
            }
        }
    }
}

// ------- reduce split-K partials (+ optional alpha*addsrc), fp32 float4 -------
__global__ void reduce_parts_kernel(const float* __restrict__ parts, size_t part_stride,
                                    int nsplit,
                                    const float* __restrict__ addsrc, const float* __restrict__ alpha,
                                    float* __restrict__ out, int count4)
{
    int i = blockIdx.x * 256 + threadIdx.x;
    if (i >= count4) return;
    f32x4 s = ((const f32x4*)parts)[i];
    for (int sp = 1; sp < nsplit; ++sp) {
        f32x4 v = *(const f32x4*)(parts + (size_t)sp * part_stride + (size_t)i * 4);
        s += v;
    }
    if (addsrc) {
        float a = alpha[0];
        f32x4 v = ((const f32x4*)addsrc)[i];
        s += v * a;
    }
    ((f32x4*)out)[i] = s;
}

extern "C" void kernel_launch(void* const* d_in, const int* in_sizes, int n_in,
                              void* d_out, int out_size, void* d_ws, size_t ws_size,
                              hipStream_t stream)
{
    const float* input  = (const float*)d_in[0];
    const float* adj    = (const float*)d_in[1];
    const float* inc    = (const float*)d_in[2];
    const float* weight = (const float*)d_in[3];
    const float* attn   = (const float*)d_in[4];
    const float* alpha  = (const float*)d_in[5];
    float* out = (float*)d_out;

    char* ws = (char*)d_ws;
    size_t off = 0;
    auto take = [&](size_t bytes) {
        char* p = ws + off;
        off = (off + bytes + 255) & ~(size_t)255;
        return p;
    };
    bf16_t* scaledT  = (bf16_t*)take((size_t)FF * NN * 2);   // scaled^T  [256][12000]
    bf16_t* supportT = (bf16_t*)take((size_t)FF * NN * 2);   // support^T [256][12000]
    bf16_t* weightT  = (bf16_t*)take((size_t)FF * FF * 2);   // weight^T  [256][256]
    float*  support4 = (float*)take((size_t)NN * FF * 4);    // adj@scaled + alpha*input
    float*  scores   = (float*)take((size_t)NN * 4);

    const size_t part_elems = (size_t)NN * FF;
    int splits = 5;
    while (splits > 1 && off + (size_t)splits * part_elems * 4 > ws_size) --splits;
    float* parts = (float*)take((size_t)splits * part_elems * 4);

    const int total_steps = NN / 32;                         // 375
    const int sps = (total_steps + splits - 1) / splits;     // 75 for splits=5
    const int mblocks = (NN + 127) / 128;                    // 94
    const int tblocks = (NN + 63) / 64;                      // 188 (transpose)
    const int red_blocks = (NN * FF / 4 + 255) / 256;

    scores_kernel<<<NN / 4, 256, 0, stream>>>(input, attn, scores);
    softmax_kernel<<<1, 1024, 0, stream>>>(scores, NN);
    transpose_scale_kernel<<<dim3(tblocks, FF / 64), 256, 0, stream>>>(input, scores, scaledT, NN);
    transpose_scale_kernel<<<dim3(FF / 64, FF / 64), 256, 0, stream>>>(weight, nullptr, weightT, FF);

    // support3 partials = adj @ scaled
    gemm_kernel<0><<<dim3(mblocks, splits), 512, 0, stream>>>(
        adj, scaledT, parts, part_elems, nullptr, NN, NN, sps, total_steps);
    // support4 = sum(partials) + alpha*input
    reduce_parts_kernel<<<red_blocks, 256, 0, stream>>>(
        parts, part_elems, splits, input, alpha, support4, NN * FF / 4);
    // support^T (bf16) = (support4 @ weight)^T
    gemm_kernel<1><<<dim3(mblocks, 1), 512, 0, stream>>>(
        support4, weightT, nullptr, 0, supportT, NN, FF, FF / 32, FF / 32);
    // output partials = incidence @ support
    gemm_kernel<0><<<dim3(mblocks, splits), 512, 0, stream>>>(
        inc, supportT, parts, part_elems, nullptr, NN, NN, sps, total_steps);
    reduce_parts_kernel<<<red_blocks, 256, 0, stream>>>(
        parts, part_elems, splits, nullptr, nullptr, out, NN * FF / 4);
}